// Round 1
// baseline (533.759 us; speedup 1.0000x reference)
//
#include <hip/hip_runtime.h>
#include <hip/hip_bf16.h>

typedef float f32x4 __attribute__((ext_vector_type(4)));
typedef short bf16x8 __attribute__((ext_vector_type(8)));

#define BM 128
#define BN 128
#define BK 32

// ---------- helpers ----------

__device__ inline unsigned short f2bf(float f) {
    // RNE f32->bf16 via intrinsic; compiler can fuse pairs into v_cvt_pk_bf16_f32
    __hip_bfloat16 h = __float2bfloat16(f);
    unsigned short s;
    __builtin_memcpy(&s, &h, 2);
    return s;
}

__device__ inline bf16x8 quant_pack8(float4 a, float4 b, float inv_scale, float zp) {
    float v[8] = {a.x, a.y, a.z, a.w, b.x, b.y, b.z, b.w};
    union { bf16x8 v8; unsigned short s[8]; } o;
#pragma unroll
    for (int j = 0; j < 8; ++j) {
        // ref: clip(round(x/scale) + zp, -128, 127); zp is integer so
        // rint(x*inv + zp) == rint(x*inv) + zp
        float t = rintf(fmaf(v[j], inv_scale, zp));
        t = fminf(127.0f, fmaxf(-128.0f, t));
        o.s[j] = f2bf(t);
    }
    return o.v8;
}

__device__ inline bf16x8 cvt_pack8(float4 a, float4 b) {
    float v[8] = {a.x, a.y, a.z, a.w, b.x, b.y, b.z, b.w};
    union { bf16x8 v8; unsigned short s[8]; } o;
#pragma unroll
    for (int j = 0; j < 8; ++j) o.s[j] = f2bf(v[j]);
    return o.v8;
}

// ---------- kernel 1: per-block min/max partials ----------

__global__ __launch_bounds__(256) void minmax_partial(const float* __restrict__ x, int n4,
                                                      float* __restrict__ pmin,
                                                      float* __restrict__ pmax) {
    float lmin = 3.4e38f, lmax = -3.4e38f;
    const float4* xv = (const float4*)x;
    int stride = gridDim.x * blockDim.x;
    for (int i = blockIdx.x * blockDim.x + threadIdx.x; i < n4; i += stride) {
        float4 v = xv[i];
        lmin = fminf(lmin, fminf(fminf(v.x, v.y), fminf(v.z, v.w)));
        lmax = fmaxf(lmax, fmaxf(fmaxf(v.x, v.y), fmaxf(v.z, v.w)));
    }
#pragma unroll
    for (int off = 32; off > 0; off >>= 1) {
        lmin = fminf(lmin, __shfl_down(lmin, off));
        lmax = fmaxf(lmax, __shfl_down(lmax, off));
    }
    __shared__ float smin[4], smax[4];
    int w = threadIdx.x >> 6;
    if ((threadIdx.x & 63) == 0) { smin[w] = lmin; smax[w] = lmax; }
    __syncthreads();
    if (threadIdx.x == 0) {
        float m0 = fminf(fminf(smin[0], smin[1]), fminf(smin[2], smin[3]));
        float m1 = fmaxf(fmaxf(smax[0], smax[1]), fmaxf(smax[2], smax[3]));
        pmin[blockIdx.x] = m0;
        pmax[blockIdx.x] = m1;
    }
}

// ---------- kernel 2: finalize scale/zp ----------

__global__ __launch_bounds__(64) void finalize_qp(const float* __restrict__ pmin,
                                                  const float* __restrict__ pmax, int nb,
                                                  float* __restrict__ hdr) {
    float lmin = 3.4e38f, lmax = -3.4e38f;
    for (int i = threadIdx.x; i < nb; i += 64) {
        lmin = fminf(lmin, pmin[i]);
        lmax = fmaxf(lmax, pmax[i]);
    }
#pragma unroll
    for (int off = 32; off > 0; off >>= 1) {
        lmin = fminf(lmin, __shfl_down(lmin, off));
        lmax = fmaxf(lmax, __shfl_down(lmax, off));
    }
    if (threadIdx.x == 0) {
        float scale = (lmax - lmin) / 255.0f;   // (QMAX-QMIN) = 255
        float zp = -128.0f - rintf(lmin / scale);
        zp = fminf(127.0f, fmaxf(-128.0f, zp));
        hdr[0] = 1.0f / scale;
        hdr[1] = zp;
    }
}

// ---------- kernel 3: fused quantize + bf16 MFMA GEMM (C = q(x) @ W^T + bias) ----------
// A = x (M x K, row-major), B = weight (N x K, row-major) -> "B^T" GEMM.
// 4 waves (2x2), each computes a 64x64 sub-tile = 4x4 fragments of 16x16x32.

__global__ __launch_bounds__(256) void qgemm_kernel(const float* __restrict__ x,
                                                    const float* __restrict__ w,
                                                    const float* __restrict__ bias,
                                                    const float* __restrict__ qp,
                                                    float* __restrict__ out,
                                                    int M, int N, int K) {
    // LDS: [k-group][row][8 bf16] so both ds_write_b128 and ds_read_b128 are
    // contiguous-16B-per-lane (conflict-free).
    __shared__ unsigned short As[4][BM][8];  // 8 KB
    __shared__ unsigned short Bs[4][BN][8];  // 8 KB

    const int tid = threadIdx.x;
    const int bm = blockIdx.y * BM;
    const int bn = blockIdx.x * BN;

    const float inv_scale = qp[0];
    const float zp = qp[1];

    const int lane = tid & 63;
    const int wid = tid >> 6;
    const int wm = (wid >> 1) * 64;   // wave row offset in tile
    const int wn = (wid & 1) * 64;    // wave col offset in tile
    const int l16 = lane & 15;
    const int kg = lane >> 4;         // 0..3

    // Staging: 512 (g,row) 16B chunks per operand; thread t owns (g=t&3, row=t>>2)
    // and (same g, row+64). Each chunk = 8 consecutive k's of one row.
    const int r0 = tid >> 2;          // 0..63
    const int g0 = tid & 3;

    const float* pa0 = x + (size_t)(bm + r0) * K + g0 * 8;
    const float* pa1 = pa0 + (size_t)64 * K;
    const float* pb0 = w + (size_t)(bn + r0) * K + g0 * 8;
    const float* pb1 = pb0 + (size_t)64 * K;

    f32x4 acc[4][4];
#pragma unroll
    for (int i = 0; i < 4; ++i)
#pragma unroll
        for (int j = 0; j < 4; ++j) acc[i][j] = (f32x4){0.f, 0.f, 0.f, 0.f};

    const int nk = K / BK;
    for (int kt = 0; kt < nk; ++kt) {
        // global f32 loads (2 x float4 per operand-row-chunk)
        float4 a00 = *(const float4*)(pa0 + 0);
        float4 a01 = *(const float4*)(pa0 + 4);
        float4 a10 = *(const float4*)(pa1 + 0);
        float4 a11 = *(const float4*)(pa1 + 4);
        float4 b00 = *(const float4*)(pb0 + 0);
        float4 b01 = *(const float4*)(pb0 + 4);
        float4 b10 = *(const float4*)(pb1 + 0);
        float4 b11 = *(const float4*)(pb1 + 4);
        pa0 += BK; pa1 += BK; pb0 += BK; pb1 += BK;

        bf16x8 qa0 = quant_pack8(a00, a01, inv_scale, zp);
        bf16x8 qa1 = quant_pack8(a10, a11, inv_scale, zp);
        bf16x8 wb0 = cvt_pack8(b00, b01);
        bf16x8 wb1 = cvt_pack8(b10, b11);

        __syncthreads();  // previous iteration's ds_reads complete

        *(bf16x8*)&As[g0][r0][0]      = qa0;
        *(bf16x8*)&As[g0][r0 + 64][0] = qa1;
        *(bf16x8*)&Bs[g0][r0][0]      = wb0;
        *(bf16x8*)&Bs[g0][r0 + 64][0] = wb1;

        __syncthreads();

        bf16x8 af[4], bf[4];
#pragma unroll
        for (int i = 0; i < 4; ++i)
            af[i] = *(const bf16x8*)&As[kg][wm + i * 16 + l16][0];
#pragma unroll
        for (int j = 0; j < 4; ++j)
            bf[j] = *(const bf16x8*)&Bs[kg][wn + j * 16 + l16][0];

#pragma unroll
        for (int i = 0; i < 4; ++i)
#pragma unroll
            for (int j = 0; j < 4; ++j)
                acc[i][j] = __builtin_amdgcn_mfma_f32_16x16x32_bf16(af[i], bf[j], acc[i][j], 0, 0, 0);
    }

    // epilogue: C/D layout col = lane&15, row = (lane>>4)*4 + r  [m89-verified]
#pragma unroll
    for (int j = 0; j < 4; ++j) {
        const int col = bn + wn + j * 16 + l16;
        const float bj = bias[col];
#pragma unroll
        for (int i = 0; i < 4; ++i) {
            const int rowb = bm + wm + i * 16 + kg * 4;
            float* po = out + (size_t)rowb * N + col;
#pragma unroll
            for (int r = 0; r < 4; ++r) po[(size_t)r * N] = acc[i][j][r] + bj;
        }
    }
}

// ---------- launch ----------

extern "C" void kernel_launch(void* const* d_in, const int* in_sizes, int n_in,
                              void* d_out, int out_size, void* d_ws, size_t ws_size,
                              hipStream_t stream) {
    const float* x    = (const float*)d_in[0];
    const float* w    = (const float*)d_in[1];
    const float* bias = (const float*)d_in[2];
    float* out = (float*)d_out;
    float* wsf = (float*)d_ws;

    const int N = in_sizes[2];            // 4096
    const int K = in_sizes[1] / N;        // 4096
    const int M = in_sizes[0] / K;        // 8192

    int nb = 1024;
    {   // stay inside ws if it is tiny (header 16 floats + 2*nb partials)
        size_t cap = ws_size / sizeof(float);
        if (cap < (size_t)(16 + 2 * nb)) {
            long avail = (long)cap - 16;
            nb = avail > 2 ? (int)(avail / 2) : 1;
        }
    }
    float* hdr  = wsf;
    float* pmin = wsf + 16;
    float* pmax = wsf + 16 + nb;

    const int n4 = in_sizes[0] / 4;
    minmax_partial<<<dim3(nb), dim3(256), 0, stream>>>(x, n4, pmin, pmax);
    finalize_qp<<<dim3(1), dim3(64), 0, stream>>>(pmin, pmax, nb, hdr);

    dim3 grid(N / BN, M / BM);
    qgemm_kernel<<<grid, dim3(256), 0, stream>>>(x, w, bias, hdr, out, M, N, K);
}